// Round 8
// baseline (946.557 us; speedup 1.0000x reference)
//
#include <hip/hip_runtime.h>

#define NROWS 32768   // B*T = 16*2048
#define DIM 256
#define KCODES 1024
#define NLEV 4

typedef float f32x16 __attribute__((ext_vector_type(16)));
typedef float f32x2  __attribute__((ext_vector_type(2)));

// ============ codebook squared norms (bit-identical to passing rounds) ============
__global__ __launch_bounds__(256) void k_bnorm(const float* __restrict__ cb,
                                               float* __restrict__ bv) {
  int r = blockIdx.x * blockDim.x + threadIdx.x;  // 0..4095
  if (r >= NLEV * KCODES) return;
  const float4* p = reinterpret_cast<const float4*>(cb + (size_t)r * DIM);
  float s0 = 0.f, s1 = 0.f, s2 = 0.f, s3 = 0.f;
  for (int g = 0; g < DIM / 4; ++g) {
    float4 v = p[g];
    s0 += v.x * v.x; s1 += v.y * v.y; s2 += v.z * v.z; s3 += v.w * v.w;
  }
  bv[r] = (s0 + s1) + (s2 + s3);
}

// ============ codebook transpose: cb[l][code][d] -> cbT[l][d][code] ============
__global__ __launch_bounds__(256) void k_tcb(const float* __restrict__ cb,
                                             float* __restrict__ cbT) {
  __shared__ __align__(16) float sh[16][272];
  const int tid = threadIdx.x;
  const int lvl = blockIdx.x >> 6;
  const int c0 = (blockIdx.x & 63) * 16;
  {
    const int cr = tid >> 4;
    const int l16 = tid & 15;
    const float4* p = reinterpret_cast<const float4*>(
        cb + ((size_t)lvl * KCODES + c0 + cr) * DIM + l16 * 16);
    #pragma unroll
    for (int j = 0; j < 4; ++j) {
      float4 v = p[j];
      sh[cr][l16 * 16 + 4 * j + 0] = v.x;
      sh[cr][l16 * 16 + 4 * j + 1] = v.y;
      sh[cr][l16 * 16 + 4 * j + 2] = v.z;
      sh[cr][l16 * 16 + 4 * j + 3] = v.w;
    }
  }
  __syncthreads();
  {
    float w[16];
    #pragma unroll
    for (int r = 0; r < 16; ++r) w[r] = sh[r][tid];
    float4* o = reinterpret_cast<float4*>(
        cbT + (size_t)lvl * (DIM * KCODES) + (size_t)tid * KCODES + c0);
    o[0] = make_float4(w[0], w[1], w[2], w[3]);
    o[1] = make_float4(w[4], w[5], w[6], w[7]);
    o[2] = make_float4(w[8], w[9], w[10], w[11]);
    o[3] = make_float4(w[12], w[13], w[14], w[15]);
  }
}

// ============ x -> residT (transpose) + rowsq ============
__global__ __launch_bounds__(256) void k_prep(const float* __restrict__ x,
                                              float* __restrict__ residT,
                                              float* __restrict__ rowsq) {
  __shared__ __align__(16) float sh[16][272];
  __shared__ float sred[256];
  const int tid = threadIdx.x;
  const int row0 = blockIdx.x * 16;
  const int rr = tid >> 4;
  const int l16 = tid & 15;
  float e = 0.f;
  {
    const float4* p = reinterpret_cast<const float4*>(
        x + (size_t)(row0 + rr) * DIM + l16 * 16);
    #pragma unroll
    for (int j = 0; j < 4; ++j) {
      float4 v = p[j];
      sh[rr][l16 * 16 + 4 * j + 0] = v.x;
      sh[rr][l16 * 16 + 4 * j + 1] = v.y;
      sh[rr][l16 * 16 + 4 * j + 2] = v.z;
      sh[rr][l16 * 16 + 4 * j + 3] = v.w;
      e += v.x * v.x + v.y * v.y + v.z * v.z + v.w * v.w;
    }
  }
  sred[tid] = e;
  __syncthreads();
  if (tid < 16) {
    float s = 0.f;
    #pragma unroll
    for (int k = 0; k < 16; ++k) s += sred[tid * 16 + k];
    rowsq[row0 + tid] = s;
  }
  {
    float w[16];
    #pragma unroll
    for (int r = 0; r < 16; ++r) w[r] = sh[r][tid];
    float4* o = reinterpret_cast<float4*>(residT + (size_t)tid * NROWS + row0);
    o[0] = make_float4(w[0], w[1], w[2], w[3]);
    o[1] = make_float4(w[4], w[5], w[6], w[7]);
    o[2] = make_float4(w[8], w[9], w[10], w[11]);
    o[3] = make_float4(w[12], w[13], w[14], w[15]);
  }
}

// pk helpers: each component is an IEEE fused FMA -> same chain as rounds 1-7.
#define PK_LO(ACC, RP, CP)                                                     \
  asm volatile("v_pk_fma_f32 %0, %1, %2, %0 op_sel:[0,0,0] op_sel_hi:[1,0,1]"  \
               : "+v"(ACC) : "s"(RP), "v"(CP))
#define PK_HI(ACC, RP, CP)                                                     \
  asm volatile("v_pk_fma_f32 %0, %1, %2, %0 op_sel:[0,1,0] op_sel_hi:[1,1,1]"  \
               : "+v"(ACC) : "s"(RP), "v"(CP))

// one d, 512 codes/lane-wave: 8 row-pairs x 8 code-slots = 64 pk_fma.
// CQ0/CQ1 = quarter0 codes (4l+0..3), CQ2/CQ3 = quarter1 (256+4l+0..3).
#define PKD2(R16, CQ0, CQ1, CQ2, CQ3)                             \
  do {                                                            \
    _Pragma("unroll")                                             \
    for (int k_ = 0; k_ < 8; ++k_) {                              \
      f32x2 rp_;                                                  \
      rp_[0] = (R16)[2 * k_]; rp_[1] = (R16)[2 * k_ + 1];         \
      PK_LO(acc2[k_][0], rp_, CQ0);                               \
      PK_HI(acc2[k_][1], rp_, CQ0);                               \
      PK_LO(acc2[k_][2], rp_, CQ1);                               \
      PK_HI(acc2[k_][3], rp_, CQ1);                               \
      PK_LO(acc2[k_][4], rp_, CQ2);                               \
      PK_HI(acc2[k_][5], rp_, CQ2);                               \
      PK_LO(acc2[k_][6], rp_, CQ3);                               \
      PK_HI(acc2[k_][7], rp_, CQ3);                               \
    }                                                             \
  } while (0)

#define ISSUE_R(R0, R1, BASE)                                          \
  asm volatile("s_load_dwordx16 %0, %2, 0x0\n\t"                       \
               "s_load_dwordx16 %1, %2, 0x20000"                       \
               : "=&s"(R0), "=&s"(R1) : "s"(BASE))

#define WAIT_R(R0, R1)                                                 \
  asm volatile("s_waitcnt lgkmcnt(0)" : "+s"(R0), "+s"(R1));           \
  __builtin_amdgcn_sched_barrier(0)

// load C (f32x2 regs, no repacking) for a 2-d batch; P in f32x2 units at d, lane applied
#define CLOAD(CS, P)                                                   \
  do {                                                                 \
    CS[0] = (P)[0];   CS[1] = (P)[1];                                  \
    CS[2] = (P)[128]; CS[3] = (P)[129];                                \
    CS[4] = (P)[512]; CS[5] = (P)[513];                                \
    CS[6] = (P)[640]; CS[7] = (P)[641];                                \
  } while (0)

// ============ fused distance + argmin, one level ============
// 1024 blocks = 512 row-tiles x 2 code-halves (halves at +512 -> same XCD).
// Wave = 16 rows x 512 codes (lane = 4 codes in each quarter of the half).
// Per 2-d batch: 128 pk_fma (~512 issue-cyc) covering one in-flight
// s_load_dwordx16 pair -> SMEM latency fully hidden per wave. Distances
// bit-identical to rounds 1-7 (same ascending-d fused chain + epilogue).
__global__ __launch_bounds__(256) void k_argmin(const float* __restrict__ residT,
                                                const float* __restrict__ cbT,
                                                const float* __restrict__ bv,
                                                const float* __restrict__ rowsq,
                                                unsigned long long* __restrict__ best) {
  const int tid = threadIdx.x;
  const int lane = tid & 63;
  const int wid = tid >> 6;
  const int rt = blockIdx.x & 511;
  const int q = blockIdx.x >> 9;          // 0..1
  const int cbase = q * 512;
  const int rowbase = rt * 64 + wid * 16;

  // wave-uniform scalar base: &residT[0][rowbase]
  const float* rp0 = residT + rowbase;
  unsigned blo = __builtin_amdgcn_readfirstlane((unsigned)(uintptr_t)rp0);
  unsigned bhi = __builtin_amdgcn_readfirstlane((unsigned)((uintptr_t)rp0 >> 32));
  unsigned long long sbase = ((unsigned long long)bhi << 32) | blo;

  f32x2 acc2[8][8];
  #pragma unroll
  for (int k = 0; k < 8; ++k)
    #pragma unroll
    for (int j = 0; j < 8; ++j) { acc2[k][j][0] = 0.f; acc2[k][j][1] = 0.f; }

  f32x16 rA0, rA1, rB0, rB1;
  f32x2 cA[8], cB[8];

  // prologue: issue R batch 0 (d=0,1), load C for d=0,1
  ISSUE_R(rA0, rA1, sbase);
  sbase += 0x40000ull;  // 2 d * 128 KB
  const f32x2* cptr = reinterpret_cast<const f32x2*>(cbT + cbase) + 2 * lane;
  CLOAD(cA, cptr);
  cptr += 1024;  // 2 d * 512 f32x2

  #pragma unroll 1
  for (int i = 0; i < 64; ++i) {
    // even batch: consume A (d=4i,4i+1); issue B (d=4i+2,4i+3)
    WAIT_R(rA0, rA1);
    ISSUE_R(rB0, rB1, sbase);
    sbase += 0x40000ull;
    CLOAD(cB, cptr);
    cptr += 1024;
    PKD2(rA0, cA[0], cA[1], cA[2], cA[3]);
    PKD2(rA1, cA[4], cA[5], cA[6], cA[7]);
    // odd batch: consume B; issue A for next iteration
    WAIT_R(rB0, rB1);
    if (i < 63) {
      ISSUE_R(rA0, rA1, sbase);
      sbase += 0x40000ull;
      CLOAD(cA, cptr);
      cptr += 1024;
    }
    PKD2(rB0, cB[0], cB[1], cB[2], cB[3]);
    PKD2(rB1, cB[4], cB[5], cB[6], cB[7]);
  }

  // epilogue: dd = fl(fl(A+B) - 2*dot); u64 (dist,idx) min over 64 lanes.
  // acc2[k][j][c] = dot(row 2k+c, code cbase + (j>=4)*256 + 4*lane + (j&3)).
  const float4 bv0 = *reinterpret_cast<const float4*>(bv + cbase + 4 * lane);
  const float4 bv1 = *reinterpret_cast<const float4*>(bv + cbase + 256 + 4 * lane);
  const int code0a = cbase + 4 * lane;
  const int code0b = cbase + 256 + 4 * lane;
  #pragma unroll
  for (int r = 0; r < 16; ++r) {
    const int k = r >> 1;
    const int c = r & 1;
    const float a = rowsq[rowbase + r];
    float t0 = a + bv0.x; float d0 = t0 - 2.0f * acc2[k][0][c];
    float t1 = a + bv0.y; float d1 = t1 - 2.0f * acc2[k][1][c];
    float t2 = a + bv0.z; float d2 = t2 - 2.0f * acc2[k][2][c];
    float t3 = a + bv0.w; float d3 = t3 - 2.0f * acc2[k][3][c];
    float t4 = a + bv1.x; float d4 = t4 - 2.0f * acc2[k][4][c];
    float t5 = a + bv1.y; float d5 = t5 - 2.0f * acc2[k][5][c];
    float t6 = a + bv1.z; float d6 = t6 - 2.0f * acc2[k][6][c];
    float t7 = a + bv1.w; float d7 = t7 - 2.0f * acc2[k][7][c];
    unsigned long long u0 = ((unsigned long long)__float_as_uint(d0) << 32) | (unsigned)(code0a + 0);
    unsigned long long u1 = ((unsigned long long)__float_as_uint(d1) << 32) | (unsigned)(code0a + 1);
    unsigned long long u2 = ((unsigned long long)__float_as_uint(d2) << 32) | (unsigned)(code0a + 2);
    unsigned long long u3 = ((unsigned long long)__float_as_uint(d3) << 32) | (unsigned)(code0a + 3);
    unsigned long long u4 = ((unsigned long long)__float_as_uint(d4) << 32) | (unsigned)(code0b + 0);
    unsigned long long u5 = ((unsigned long long)__float_as_uint(d5) << 32) | (unsigned)(code0b + 1);
    unsigned long long u6 = ((unsigned long long)__float_as_uint(d6) << 32) | (unsigned)(code0b + 2);
    unsigned long long u7 = ((unsigned long long)__float_as_uint(d7) << 32) | (unsigned)(code0b + 3);
    unsigned long long u = u0 < u1 ? u0 : u1;
    u = u2 < u ? u2 : u;
    u = u3 < u ? u3 : u;
    u = u4 < u ? u4 : u;
    u = u5 < u ? u5 : u;
    u = u6 < u ? u6 : u;
    u = u7 < u ? u7 : u;
    #pragma unroll
    for (int m = 1; m < 64; m <<= 1) {
      unsigned long long o = __shfl_xor(u, m);
      u = (o < u) ? o : u;
    }
    if (lane == 0) atomicMin(best + rowbase + r, u);
  }
}

// ============ residual update (T layout) + quant accum + losses ============
__global__ __launch_bounds__(256) void k_update(float* __restrict__ residT,
                                                const float* __restrict__ cb,
                                                const unsigned long long* __restrict__ best,
                                                float* __restrict__ tq,
                                                float* __restrict__ fidx,
                                                float* __restrict__ part,
                                                float* __restrict__ rowsq,
                                                const float* __restrict__ x,
                                                int lvl) {
  __shared__ __align__(16) float sh[16][272];
  __shared__ float sred[256];
  const int tid = threadIdx.x;
  const int row0 = blockIdx.x * 16;

  {
    const float4* p = reinterpret_cast<const float4*>(residT + (size_t)tid * NROWS + row0);
    float4 a0 = p[0], a1 = p[1], a2 = p[2], a3 = p[3];
    sh[0][tid] = a0.x;  sh[1][tid] = a0.y;  sh[2][tid] = a0.z;  sh[3][tid] = a0.w;
    sh[4][tid] = a1.x;  sh[5][tid] = a1.y;  sh[6][tid] = a1.z;  sh[7][tid] = a1.w;
    sh[8][tid] = a2.x;  sh[9][tid] = a2.y;  sh[10][tid] = a2.z; sh[11][tid] = a2.w;
    sh[12][tid] = a3.x; sh[13][tid] = a3.y; sh[14][tid] = a3.z; sh[15][tid] = a3.w;
  }
  __syncthreads();

  const int rr = tid >> 4;
  const int l16 = tid & 15;
  const int row = row0 + rr;
  const int id = (int)(best[row] & 0xffffffffull);
  float nn[16];
  float e = 0.f;
  {
    const float4* cp = reinterpret_cast<const float4*>(cb + (size_t)id * DIM + l16 * 16);
    const size_t obase = (size_t)row * DIM + l16 * 16;
    float4* tp = reinterpret_cast<float4*>(tq + obase);
    const float4* xp = reinterpret_cast<const float4*>(x + obase);
    #pragma unroll
    for (int j = 0; j < 4; ++j) {
      float4 c = cp[j];
      float r0 = sh[rr][l16 * 16 + 4 * j + 0];
      float r1 = sh[rr][l16 * 16 + 4 * j + 1];
      float r2 = sh[rr][l16 * 16 + 4 * j + 2];
      float r3 = sh[rr][l16 * 16 + 4 * j + 3];
      float n0 = r0 - c.x, n1 = r1 - c.y, n2 = r2 - c.z, n3 = r3 - c.w;
      nn[4 * j + 0] = n0; nn[4 * j + 1] = n1; nn[4 * j + 2] = n2; nn[4 * j + 3] = n3;
      e += (n0 * n0 + n1 * n1) + (n2 * n2 + n3 * n3);
      float4 tv;
      if (lvl == 0) {
        tv = c;
      } else {
        tv = tp[j];
        tv.x += c.x; tv.y += c.y; tv.z += c.z; tv.w += c.w;
      }
      if (lvl == 3) {
        float4 xv = xp[j];
        tv.x = xv.x + (tv.x - xv.x); tv.y = xv.y + (tv.y - xv.y);
        tv.z = xv.z + (tv.z - xv.z); tv.w = xv.w + (tv.w - xv.w);
      }
      tp[j] = tv;
    }
  }
  sred[tid] = e;
  if (l16 == 0) fidx[row] = (float)id;
  __syncthreads();

  __shared__ float rsum[16];
  if (tid < 16) {
    float s = 0.f;
    #pragma unroll
    for (int k = 0; k < 16; ++k) s += sred[tid * 16 + k];
    rsum[tid] = s;
    if (lvl < 3) rowsq[row0 + tid] = s;
  }
  __syncthreads();
  if (tid == 0) {
    float p = 0.f;
    #pragma unroll
    for (int k = 0; k < 16; ++k) p += rsum[k];
    part[blockIdx.x] = p;
  }

  if (lvl < 3) {
    #pragma unroll
    for (int k = 0; k < 16; ++k) sh[rr][l16 * 16 + k] = nn[k];
    __syncthreads();
    float w[16];
    #pragma unroll
    for (int r = 0; r < 16; ++r) w[r] = sh[r][tid];
    float4* o = reinterpret_cast<float4*>(residT + (size_t)tid * NROWS + row0);
    o[0] = make_float4(w[0], w[1], w[2], w[3]);
    o[1] = make_float4(w[4], w[5], w[6], w[7]);
    o[2] = make_float4(w[8], w[9], w[10], w[11]);
    o[3] = make_float4(w[12], w[13], w[14], w[15]);
  }
}

// ============ loss finalize ============
__global__ __launch_bounds__(256) void k_loss(const float* __restrict__ part,
                                              float* __restrict__ out) {
  __shared__ float s[256];
  const int tid = threadIdx.x;
  float means[4];
  for (int l = 0; l < 4; ++l) {
    float sum = 0.f;
    for (int i = tid; i < 2048; i += 256) sum += part[l * 2048 + i];
    s[tid] = sum;
    __syncthreads();
    for (int st = 128; st > 0; st >>= 1) {
      if (tid < st) s[tid] += s[tid + st];
      __syncthreads();
    }
    means[l] = s[0] * (1.0f / 8388608.0f);  // /(N*D), exact pow2
    __syncthreads();
  }
  if (tid == 0) {
    float t = ((means[0] + means[1]) + means[2]) + means[3];
    float loss = t * 0.25f;
    out[0] = loss;
    out[1] = loss;
  }
}

extern "C" void kernel_launch(void* const* d_in, const int* in_sizes, int n_in,
                              void* d_out, int out_size, void* d_ws, size_t ws_size,
                              hipStream_t stream) {
  const float* x  = (const float*)d_in[0];
  const float* cb = (const float*)d_in[1];
  float* out = (float*)d_out;
  float* ws  = (float*)d_ws;

  // ws layout (float units)
  float* residT = ws;                                   // 8388608
  unsigned long long* best4 = (unsigned long long*)(ws + 8388608);  // 131072 u64
  float* part  = ws + 8388608 + 262144;                 // 4*2048
  float* bv    = ws + 8388608 + 262144 + 8192;          // 4096
  float* rowsq = ws + 8388608 + 262144 + 8192 + 4096;   // 32768
  float* cbT   = ws + 8388608 + 262144 + 8192 + 4096 + 32768;  // 4*262144

  float* tq      = out;                    // total_quant accumulates in d_out
  float* lossout = out + 8388608;
  float* fidx    = out + 8388610;

  hipMemsetAsync(best4, 0xFF, (size_t)NLEV * NROWS * 8, stream);
  k_bnorm<<<16, 256, 0, stream>>>(cb, bv);
  k_tcb<<<256, 256, 0, stream>>>(cb, cbT);
  k_prep<<<2048, 256, 0, stream>>>(x, residT, rowsq);

  for (int l = 0; l < NLEV; ++l) {
    const float* cbl  = cb  + (size_t)l * KCODES * DIM;
    const float* cbTl = cbT + (size_t)l * KCODES * DIM;
    k_argmin<<<1024, 256, 0, stream>>>(residT, cbTl, bv + l * KCODES, rowsq,
                                       best4 + (size_t)l * NROWS);
    k_update<<<2048, 256, 0, stream>>>(residT, cbl, best4 + (size_t)l * NROWS,
                                       tq, fidx + (size_t)l * NROWS,
                                       part + l * 2048, rowsq, x, l);
  }

  k_loss<<<1, 256, 0, stream>>>(part, lossout);
}